// Round 4
// baseline (446.615 us; speedup 1.0000x reference)
//
#include <hip/hip_runtime.h>
#include <hip/hip_bf16.h>
#include <math.h>

#define B_ 4
#define S_ 2048
#define D_ 512
#define H_ 8
#define K_ 512
#define F_ 2048
#define NT 8192     // B*S tokens
#define HK 4096     // H*K
#define HG 2        // heads per group
#define NGROUP 4    // H/HG
#define GN 1024     // HG*K columns per group
#define G3 3072     // 3*GN

typedef __attribute__((ext_vector_type(8))) short bf16x8;
typedef __attribute__((ext_vector_type(4))) float f32x4;
typedef unsigned short u16;

__device__ __forceinline__ float bits2f(u16 b) {
  union { unsigned u; float f; } c; c.u = ((unsigned)b) << 16; return c.f;
}
__device__ __forceinline__ u16 f2bfbits(float f) {
  union { float f; unsigned u; } c; c.f = f;
  unsigned r = c.u + 0x7fffu + ((c.u >> 16) & 1u);
  return (u16)(r >> 16);
}

__device__ __forceinline__ void gload16(const void* g, void* lds) {
  __builtin_amdgcn_global_load_lds(
      (const __attribute__((address_space(1))) unsigned int*)g,
      (__attribute__((address_space(3))) unsigned int*)lds, 16, 0, 0);
}

#define BARR asm volatile("s_barrier" ::: "memory")
#define VMC(n) asm volatile("s_waitcnt vmcnt(" #n ")" ::: "memory")

// ---------------------------------------------------------------------------
// fp32 -> bf16 elementwise (x conversion)
// ---------------------------------------------------------------------------
__global__ __launch_bounds__(256) void conv_f32_bf16(const float* __restrict__ in,
                                                     u16* __restrict__ out, int n4) {
  int i = blockIdx.x * 256 + threadIdx.x;
  if (i < n4) {
    float4 f = ((const float4*)in)[i];
    ushort4 o;
    o.x = f2bfbits(f.x); o.y = f2bfbits(f.y); o.z = f2bfbits(f.z); o.w = f2bfbits(f.w);
    ((ushort4*)out)[i] = o;
  }
}

// ---------------------------------------------------------------------------
// fp32 (rows x cols, leading dim ldin) -> bf16 transposed (cols x rows)
// ---------------------------------------------------------------------------
__global__ __launch_bounds__(256) void transpose_f32_bf16(const float* __restrict__ in,
                                                          int ldin,
                                                          u16* __restrict__ out,
                                                          int rows, int cols) {
  __shared__ float tile[32][33];
  const int tx = threadIdx.x & 31;
  const int ty = threadIdx.x >> 5;          // 0..7
  const int rb = blockIdx.y * 32;
  const int cb = blockIdx.x * 32;
  for (int i = ty; i < 32; i += 8)
    tile[i][tx] = in[(size_t)(rb + i) * ldin + cb + tx];
  __syncthreads();
  for (int i = ty; i < 32; i += 8)
    out[(size_t)(cb + i) * rows + rb + tx] = f2bfbits(tile[tx][i]);
}

// ---------------------------------------------------------------------------
// concat per-group qkv bias: o[g][part][GN], part 0=q 1=k 2=v
// ---------------------------------------------------------------------------
__global__ __launch_bounds__(256) void qkv_bias_cat(const float* __restrict__ bq,
                                                    const float* __restrict__ bk,
                                                    const float* __restrict__ bv,
                                                    float* __restrict__ o) {
  int i = blockIdx.x * 256 + threadIdx.x;   // < NGROUP*G3
  int g = i / G3, r = i % G3;
  int part = r / GN, off = r % GN;
  const float* src = (part == 0) ? bq : (part == 1) ? bk : bv;
  o[i] = src[g * GN + off];
}

// ---------------------------------------------------------------------------
// bf16 GEMM, 256x256 tile, BK=64, 8 waves (2M x 4N), 8-phase counted-vmcnt
// schedule (T3+T4+T5), T2 XOR swizzle via pre-swizzled global source.
// Per iteration: 2 K-tiles (buf0 phases 1-4 quadrants (0,0)(0,1)(1,0)(1,1);
// buf1 phases 5-8 reversed). Staging stagger (quarter = 64 rows, 1 ld/thr):
//   ph1:[b1.A0,A2,B0,B1 t+1] ph2:[b1.B2,B3 t+1] ph3:[b0.A0,A2 t+2]
//   ph5:[b0.A1,A3,B0,B1 t+2] ph6:[b0.B2,B3 t+2] ph7:[b1.A1,A3 t+3]
// Every stage targets a region last read >=1 phase (2 barriers) earlier.
// vmcnt(2) at ph1/ph5 (tail: vmcnt(0) at ph5) BEFORE that phase's stages,
// before barrier -> per-wave retire + barrier = cross-wave visibility.
// OUTBF: 1 = bf16 store (+bias)(+gelu), 0 = f32 partial store (split-K).
// ---------------------------------------------------------------------------
template <int BIAS, int GELU, int OUTBF>
__global__ __launch_bounds__(512, 2) void gemm8p(const u16* __restrict__ A, int lda,
                                                 const u16* __restrict__ Bt, int ldb,
                                                 const float* __restrict__ bias,
                                                 float* __restrict__ Cf, size_t zstride,
                                                 u16* __restrict__ Cb, int ldc,
                                                 int kslice) {
  __shared__ short lds[2][32768];   // per buf: A[256][64] @0, B[256][64] @16384
  const int tid = threadIdx.x;
  const int lane = tid & 63;
  const int wave = tid >> 6;        // 0..7
  const int bm = blockIdx.x * 256;
  const int bn = blockIdx.y * 256;
  const int k0 = blockIdx.z * kslice;

  const int wr = (wave >> 2) * 128; // wave row base (2 M-waves)
  const int wc = (wave & 3) * 64;   // wave col base (4 N-waves)

  f32x4 acc[8][4] = {};

  // staging: quarter q (64 rows) of A/B for K-tile t; 1 gload16 per thread.
  // wave v covers rows q*64+v*8 .. +8; lane l -> row +(l>>3), chunk l&7.
  const int srow = wave * 8 + (lane >> 3);
  const int scol = ((lane & 7) ^ (lane >> 3)) * 8;    // swizzled source col
  const u16* ag = A + (size_t)(bm + srow) * lda + scol;
  const u16* bg = Bt + (size_t)(bn + srow) * ldb + scol;

  auto SQA = [&](int buf, int q, int t) {
    gload16(ag + (size_t)(q * 64) * lda + k0 + t * 64,
            &lds[buf][(q * 64 + wave * 8) * 64]);
  };
  auto SQB = [&](int buf, int q, int t) {
    gload16(bg + (size_t)(q * 64) * ldb + k0 + t * 64,
            &lds[buf][16384 + (q * 64 + wave * 8) * 64]);
  };

  bf16x8 fa[2][4], fb[2][2];
  auto LD = [&](const short* sA, const short* sB, int qr, int qc) {
#pragma unroll
    for (int ks = 0; ks < 2; ++ks) {
      const int kos = (ks * 32 + (lane >> 4) * 8) ^ ((lane & 7) << 3);
#pragma unroll
      for (int m = 0; m < 4; ++m)
        fa[ks][m] = *(const bf16x8*)&sA[(wr + qr * 64 + m * 16 + (lane & 15)) * 64 + kos];
#pragma unroll
      for (int n = 0; n < 2; ++n)
        fb[ks][n] = *(const bf16x8*)&sB[(wc + qc * 32 + n * 16 + (lane & 15)) * 64 + kos];
    }
  };
  auto FM = [&](int qr, int qc) {
    __builtin_amdgcn_s_setprio(1);
#pragma unroll
    for (int ks = 0; ks < 2; ++ks)
#pragma unroll
      for (int m = 0; m < 4; ++m)
#pragma unroll
        for (int n = 0; n < 2; ++n)
          acc[qr * 4 + m][qc * 2 + n] = __builtin_amdgcn_mfma_f32_16x16x32_bf16(
              fa[ks][m], fb[ks][n], acc[qr * 4 + m][qc * 2 + n], 0, 0, 0);
    __builtin_amdgcn_s_setprio(0);
  };

  const short* sA0 = &lds[0][0];     const short* sB0 = &lds[0][16384];
  const short* sA1 = &lds[1][0];     const short* sB1 = &lds[1][16384];

  const int nt = kslice >> 6;        // K-tiles (even, >=2)
  const int niter = nt >> 1;

  // prologue: tile0 full (8 quarters), tile1 A1,A3
  SQA(0, 0, 0); SQA(0, 2, 0); SQB(0, 0, 0); SQB(0, 1, 0);
  SQB(0, 2, 0); SQB(0, 3, 0); SQA(0, 1, 0); SQA(0, 3, 0);
  SQA(1, 1, 1); SQA(1, 3, 1);

  for (int it = 0; it < niter; ++it) {
    const int t0 = 2 * it;
    const bool mn = (it + 1 < niter);
    // ph1 (boundary): compute b0 (0,0); stage b1.A0,A2,B0,B1 of t0+1
    VMC(2);
    SQA(1, 0, t0 + 1); SQA(1, 2, t0 + 1); SQB(1, 0, t0 + 1); SQB(1, 1, t0 + 1);
    BARR;
    LD(sA0, sB0, 0, 0); FM(0, 0); BARR;
    // ph2: stage b1.B2,B3 of t0+1
    LD(sA0, sB0, 0, 1);
    SQB(1, 2, t0 + 1); SQB(1, 3, t0 + 1);
    BARR; FM(0, 1); BARR;
    // ph3: stage b0.A0,A2 of t0+2
    LD(sA0, sB0, 1, 0);
    if (mn) { SQA(0, 0, t0 + 2); SQA(0, 2, t0 + 2); }
    BARR; FM(1, 0); BARR;
    // ph4
    LD(sA0, sB0, 1, 1);
    BARR; FM(1, 1); BARR;
    // ph5 (boundary): compute b1 (1,1); stage b0.A1,A3,B0,B1 of t0+2
    if (mn) {
      VMC(2);
      SQA(0, 1, t0 + 2); SQA(0, 3, t0 + 2); SQB(0, 0, t0 + 2); SQB(0, 1, t0 + 2);
    } else {
      VMC(0);
    }
    BARR;
    LD(sA1, sB1, 1, 1); FM(1, 1); BARR;
    // ph6: stage b0.B2,B3 of t0+2
    LD(sA1, sB1, 1, 0);
    if (mn) { SQB(0, 2, t0 + 2); SQB(0, 3, t0 + 2); }
    BARR; FM(1, 0); BARR;
    // ph7: stage b1.A1,A3 of t0+3
    LD(sA1, sB1, 0, 1);
    if (mn) { SQA(1, 1, t0 + 3); SQA(1, 3, t0 + 3); }
    BARR; FM(0, 1); BARR;
    // ph8
    LD(sA1, sB1, 0, 0);
    BARR; FM(0, 0); BARR;
  }

  float* Cfz = Cf + (size_t)blockIdx.z * zstride;
#pragma unroll
  for (int m = 0; m < 8; ++m) {
    const int row0 = bm + wr + m * 16 + (lane >> 4) * 4;
#pragma unroll
    for (int n = 0; n < 4; ++n) {
      const int col = bn + wc + n * 16 + (lane & 15);
      float badd = BIAS ? bias[col] : 0.f;
      f32x4 a4 = acc[m][n];
#pragma unroll
      for (int r = 0; r < 4; ++r) {
        float vv = a4[r] + badd;
        if (GELU) vv = 0.5f * vv * (1.f + erff(vv * 0.70710678118f));
        size_t idx = (size_t)(row0 + r) * ldc + col;
        if (OUTBF) Cb[idx] = f2bfbits(vv);
        else Cfz[idx] = vv;
      }
    }
  }
}

// ---------------------------------------------------------------------------
// Windowed (tridiagonal) attention for one head-group.
// One wave per (token, head-in-group). qkv: (NT, 3GN) bf16 [q|k|v blocks].
// ---------------------------------------------------------------------------
__global__ __launch_bounds__(256) void attn_window(const u16* __restrict__ qkv,
                                                   u16* __restrict__ ctx) {
  const int lane = threadIdx.x & 63;
  const int gw = blockIdx.x * 4 + (threadIdx.x >> 6);
  const int hh = gw % HG;
  const int t = gw / HG;
  const int s = t % S_;
  const size_t qb = (size_t)t * G3 + hh * K_ + lane * 8;

  float qf[8];
  {
    bf16x8 q8 = *(const bf16x8*)(qkv + qb);
#pragma unroll
    for (int e = 0; e < 8; ++e) qf[e] = bits2f((u16)q8[e]);
  }

  const bool val0 = (s > 0), val2 = (s < S_ - 1);
  float dot[3] = {0.f, 0.f, 0.f};
  float vf[3][8];
#pragma unroll
  for (int j = 0; j < 3; ++j) {
    if ((j == 0 && !val0) || (j == 2 && !val2)) continue;
    const size_t nb = qb + (size_t)(j - 1) * G3;
    bf16x8 k8 = *(const bf16x8*)(qkv + nb + GN);
    bf16x8 v8 = *(const bf16x8*)(qkv + nb + 2 * GN);
    float d = 0.f;
#pragma unroll
    for (int e = 0; e < 8; ++e) {
      d += qf[e] * bits2f((u16)k8[e]);
      vf[j][e] = bits2f((u16)v8[e]);
    }
    dot[j] = d;
  }
#pragma unroll
  for (int j = 0; j < 3; ++j) {
    float d = dot[j];
    for (int m = 32; m >= 1; m >>= 1) d += __shfl_xor(d, m);
    dot[j] = d;
  }
  const float scale = 0.044194173824159f;  // 1/sqrt(512)
  float sc[3];
  sc[0] = val0 ? dot[0] * scale : -1e30f;
  sc[1] = dot[1] * scale;
  sc[2] = val2 ? dot[2] * scale : -1e30f;
  float mx = fmaxf(sc[0], fmaxf(sc[1], sc[2]));
  float p[3], sum = 0.f;
#pragma unroll
  for (int j = 0; j < 3; ++j) {
    p[j] = (sc[j] > -1e29f) ? expf(sc[j] - mx) : 0.f;
    sum += p[j];
  }
  const float inv = 1.f / sum;
  float o[8] = {0.f, 0.f, 0.f, 0.f, 0.f, 0.f, 0.f, 0.f};
#pragma unroll
  for (int j = 0; j < 3; ++j) {
    if ((j == 0 && !val0) || (j == 2 && !val2)) continue;
    const float pj = p[j] * inv;
#pragma unroll
    for (int e = 0; e < 8; ++e) o[e] += pj * vf[j][e];
  }
  bf16x8 o8;
#pragma unroll
  for (int e = 0; e < 8; ++e) o8[e] = (short)f2bfbits(o[e]);
  *(bf16x8*)(ctx + (size_t)t * HK + hh * K_ + lane * 8) = o8;
}

// ---------------------------------------------------------------------------
// y = xres + sum(parts) (+bias); out = LN(y)*gamma+beta -> fp32 / bf16
// ---------------------------------------------------------------------------
__global__ __launch_bounds__(256) void resid_ln(const float* __restrict__ xres,
                                                const float* __restrict__ parts,
                                                int nparts, size_t pstride,
                                                const float* __restrict__ bias,
                                                const float* __restrict__ gamma,
                                                const float* __restrict__ beta,
                                                float* __restrict__ outf,
                                                u16* __restrict__ outb) {
  const int row = blockIdx.x;
  const int tid = threadIdx.x;
  const size_t base = (size_t)row * D_;
  float2 xv = ((const float2*)(xres + base))[tid];
  float y0 = xv.x, y1 = xv.y;
  for (int p = 0; p < nparts; ++p) {
    float2 pv = ((const float2*)(parts + p * pstride + base))[tid];
    y0 += pv.x; y1 += pv.y;
  }
  if (bias) {
    float2 bv = ((const float2*)bias)[tid];
    y0 += bv.x; y1 += bv.y;
  }
  float s = y0 + y1, ss = y0 * y0 + y1 * y1;
  for (int m = 32; m >= 1; m >>= 1) { s += __shfl_xor(s, m); ss += __shfl_xor(ss, m); }
  __shared__ float red[8];
  const int wave = tid >> 6, lane = tid & 63;
  if (lane == 0) { red[wave] = s; red[4 + wave] = ss; }
  __syncthreads();
  s = red[0] + red[1] + red[2] + red[3];
  ss = red[4] + red[5] + red[6] + red[7];
  const float mean = s * (1.f / D_);
  const float var = ss * (1.f / D_) - mean * mean;
  const float rstd = rsqrtf(var + 1e-3f);
  float2 gv = ((const float2*)gamma)[tid];
  float2 bev = ((const float2*)beta)[tid];
  float o0 = (y0 - mean) * rstd * gv.x + bev.x;
  float o1 = (y1 - mean) * rstd * gv.y + bev.y;
  if (outf) { float2 of; of.x = o0; of.y = o1; ((float2*)(outf + base))[tid] = of; }
  if (outb) { ushort2 ob; ob.x = f2bfbits(o0); ob.y = f2bfbits(o1); ((ushort2*)(outb + base))[tid] = ob; }
}

// ---------------------------------------------------------------------------
extern "C" void kernel_launch(void* const* d_in, const int* in_sizes, int n_in,
                              void* d_out, int out_size, void* d_ws, size_t ws_size,
                              hipStream_t stream) {
  const float* x  = (const float*)d_in[0];
  const float* Wq = (const float*)d_in[1];
  const float* bq = (const float*)d_in[2];
  const float* Wk = (const float*)d_in[3];
  const float* bk = (const float*)d_in[4];
  const float* Wv = (const float*)d_in[5];
  const float* bv = (const float*)d_in[6];
  const float* Wo = (const float*)d_in[7];
  const float* bo = (const float*)d_in[8];
  const float* W1 = (const float*)d_in[9];
  const float* b1 = (const float*)d_in[10];
  const float* W2 = (const float*)d_in[11];
  const float* b2 = (const float*)d_in[12];
  const float* g1 = (const float*)d_in[13];
  const float* be1 = (const float*)d_in[14];
  const float* g2 = (const float*)d_in[15];
  const float* be2 = (const float*)d_in[16];
  float* out = (float*)d_out;

  char* w = (char*)d_ws;
  size_t o = 0;
  auto nxt = [&](size_t bytes) -> char* {
    char* p = w + o;
    o += (bytes + 255) & ~(size_t)255;
    return p;
  };
  u16* xb     = (u16*)nxt((size_t)NT * D_ * 2);
  u16* wqkvt  = (u16*)nxt((size_t)3 * HK * D_ * 2);   // [g][3][GN][D]
  u16* wot    = (u16*)nxt((size_t)D_ * HK * 2);
  u16* w1t    = (u16*)nxt((size_t)F_ * D_ * 2);
  u16* w2t    = (u16*)nxt((size_t)D_ * F_ * 2);
  float* qkvbias = (float*)nxt((size_t)NGROUP * G3 * 4);
  u16* qkvg   = (u16*)nxt((size_t)NT * G3 * 2);       // 50.3MB
  char* extraA = nxt((size_t)NT * D_ * 4);            // 16.8MB pad after qkvg
  u16* ctxb   = (u16*)nxt((size_t)NT * HK * 2);       // 67.1MB
  float* out1f = (float*)nxt((size_t)NT * D_ * 4);
  u16* out1b   = (u16*)nxt((size_t)NT * D_ * 2);
  (void)extraA;
  float* woP  = (float*)qkvg;   // 4x f32 WO partials (qkvg+extraA region)
  u16*   hb   = (u16*)qkvg;     // FFN1 output, live after LN1
  float* ffnP = (float*)ctxb;   // FFN2 partials (ctxb region)

  // --- input/weight conversions ---
  conv_f32_bf16<<<dim3(NT * D_ / 4 / 256), 256, 0, stream>>>(x, xb, NT * D_ / 4);
  for (int g = 0; g < NGROUP; ++g) {
    transpose_f32_bf16<<<dim3(GN / 32, D_ / 32), 256, 0, stream>>>(
        Wq + g * GN, HK, wqkvt + ((size_t)(g * 3 + 0) * GN) * D_, D_, GN);
    transpose_f32_bf16<<<dim3(GN / 32, D_ / 32), 256, 0, stream>>>(
        Wk + g * GN, HK, wqkvt + ((size_t)(g * 3 + 1) * GN) * D_, D_, GN);
    transpose_f32_bf16<<<dim3(GN / 32, D_ / 32), 256, 0, stream>>>(
        Wv + g * GN, HK, wqkvt + ((size_t)(g * 3 + 2) * GN) * D_, D_, GN);
  }
  transpose_f32_bf16<<<dim3(D_ / 32, HK / 32), 256, 0, stream>>>(Wo, D_, wot, HK, D_);
  transpose_f32_bf16<<<dim3(F_ / 32, D_ / 32), 256, 0, stream>>>(W1, F_, w1t, D_, F_);
  transpose_f32_bf16<<<dim3(D_ / 32, F_ / 32), 256, 0, stream>>>(W2, D_, w2t, F_, D_);
  qkv_bias_cat<<<dim3(NGROUP * G3 / 256), 256, 0, stream>>>(bq, bk, bv, qkvbias);

  // --- attention by head-groups: fused QKV gemm -> windowed attn ---
  for (int g = 0; g < NGROUP; ++g) {
    gemm8p<1, 0, 1><<<dim3(32, G3 / 256, 1), 512, 0, stream>>>(
        xb, D_, wqkvt + (size_t)g * G3 * D_, D_, qkvbias + g * G3,
        nullptr, 0, qkvg, G3, D_);
    attn_window<<<dim3(NT * HG / 4), 256, 0, stream>>>(qkvg, ctxb + (size_t)g * HG * K_);
  }

  // --- WO: woP[z] = ctx @ Wo (split-K=4 partials, no atomics) ---
  gemm8p<0, 0, 0><<<dim3(32, 2, 4), 512, 0, stream>>>(
      ctxb, HK, wot, HK, nullptr, woP, (size_t)NT * D_, nullptr, D_, 1024);

  // --- LN1: out1 = LN(x + sum(woP) + bo) ---
  resid_ln<<<dim3(NT), 256, 0, stream>>>(x, woP, 4, (size_t)NT * D_, bo,
                                         g1, be1, out1f, out1b);

  // --- FFN1: hb = gelu(out1 @ W1 + b1) ---
  gemm8p<1, 1, 1><<<dim3(32, F_ / 256, 1), 512, 0, stream>>>(
      out1b, D_, w1t, D_, b1, nullptr, 0, hb, F_, D_);

  // --- FFN2: ffnP[z] = hb @ W2 (split-K=4 partials; b2 folded into LN2) ---
  gemm8p<0, 0, 0><<<dim3(32, 2, 4), 512, 0, stream>>>(
      hb, F_, w2t, F_, nullptr, ffnP, (size_t)NT * D_, nullptr, D_, 512);

  // --- LN2: out = LN(out1 + sum(ffnP) + b2) ---
  resid_ln<<<dim3(NT), 256, 0, stream>>>(out1f, ffnP, 4, (size_t)NT * D_, b2,
                                         g2, be2, out, nullptr);

  (void)in_sizes; (void)n_in; (void)out_size; (void)ws_size;
}

// Round 5
// 399.336 us; speedup vs baseline: 1.1184x; 1.1184x over previous
//
#include <hip/hip_runtime.h>
#include <hip/hip_bf16.h>
#include <math.h>

#define B_ 4
#define S_ 2048
#define D_ 512
#define H_ 8
#define K_ 512
#define F_ 2048
#define NT 8192     // B*S tokens
#define HK 4096     // H*K
#define HG 2        // heads per group
#define NGROUP 4    // H/HG
#define GN 1024     // HG*K columns per group
#define G3 3072     // 3*GN

typedef __attribute__((ext_vector_type(8))) short bf16x8;
typedef __attribute__((ext_vector_type(4))) float f32x4;
typedef unsigned short u16;

__device__ __forceinline__ float bits2f(u16 b) {
  union { unsigned u; float f; } c; c.u = ((unsigned)b) << 16; return c.f;
}
__device__ __forceinline__ u16 f2bfbits(float f) {
  union { float f; unsigned u; } c; c.f = f;
  unsigned r = c.u + 0x7fffu + ((c.u >> 16) & 1u);
  return (u16)(r >> 16);
}

__device__ __forceinline__ void gload16(const void* g, void* lds) {
  __builtin_amdgcn_global_load_lds(
      (const __attribute__((address_space(1))) unsigned int*)g,
      (__attribute__((address_space(3))) unsigned int*)lds, 16, 0, 0);
}

// ---------------------------------------------------------------------------
// fp32 -> bf16 elementwise (x conversion)
// ---------------------------------------------------------------------------
__global__ __launch_bounds__(256) void conv_f32_bf16(const float* __restrict__ in,
                                                     u16* __restrict__ out, int n4) {
  int i = blockIdx.x * 256 + threadIdx.x;
  if (i < n4) {
    float4 f = ((const float4*)in)[i];
    ushort4 o;
    o.x = f2bfbits(f.x); o.y = f2bfbits(f.y); o.z = f2bfbits(f.z); o.w = f2bfbits(f.w);
    ((ushort4*)out)[i] = o;
  }
}

// ---------------------------------------------------------------------------
// fp32 (rows x cols, leading dim ldin) -> bf16 transposed (cols x rows)
// ---------------------------------------------------------------------------
__global__ __launch_bounds__(256) void transpose_f32_bf16(const float* __restrict__ in,
                                                          int ldin,
                                                          u16* __restrict__ out,
                                                          int rows, int cols) {
  __shared__ float tile[32][33];
  const int tx = threadIdx.x & 31;
  const int ty = threadIdx.x >> 5;          // 0..7
  const int rb = blockIdx.y * 32;
  const int cb = blockIdx.x * 32;
  for (int i = ty; i < 32; i += 8)
    tile[i][tx] = in[(size_t)(rb + i) * ldin + cb + tx];
  __syncthreads();
  for (int i = ty; i < 32; i += 8)
    out[(size_t)(cb + i) * rows + rb + tx] = f2bfbits(tile[tx][i]);
}

// ---------------------------------------------------------------------------
// concat per-group qkv bias: o[g][part][GN], part 0=q 1=k 2=v
// ---------------------------------------------------------------------------
__global__ __launch_bounds__(256) void qkv_bias_cat(const float* __restrict__ bq,
                                                    const float* __restrict__ bk,
                                                    const float* __restrict__ bv,
                                                    float* __restrict__ o) {
  int i = blockIdx.x * 256 + threadIdx.x;   // < NGROUP*G3
  int g = i / G3, r = i % G3;
  int part = r / GN, off = r % GN;
  const float* src = (part == 0) ? bq : (part == 1) ? bk : bv;
  o[i] = src[g * GN + off];
}

// ---------------------------------------------------------------------------
// bf16 GEMM, 128x128 tile, BK=64, 4 waves (2x2 of 64x64), double-buffered
// LDS (64KB -> 2 blocks/CU for cross-block overlap), 2-phase pipeline:
// issue next tile's global_load_lds BEFORE computing the current tile;
// single __syncthreads() per K-tile. T2 XOR swizzle via pre-swizzled global
// source + swizzled LDS read (proven 0-conflict in r2/r3).
// OUTBF: 1 = bf16 store (+bias)(+gelu), 0 = f32 partial store at
//        Cf + blockIdx.z * zstride (split-K).
// ---------------------------------------------------------------------------
template <int BIAS, int GELU, int OUTBF>
__global__ __launch_bounds__(256) void gemm128d(const u16* __restrict__ A, int lda,
                                                const u16* __restrict__ Bt, int ldb,
                                                const float* __restrict__ bias,
                                                float* __restrict__ Cf, size_t zstride,
                                                u16* __restrict__ Cb, int ldc,
                                                int kslice) {
  __shared__ short lds[2][16384];   // per buf: A[128][64] @0, B[128][64] @8192
  const int tid = threadIdx.x;
  const int lane = tid & 63;
  const int wave = tid >> 6;        // 0..3
  const int bm = blockIdx.x * 128;
  const int bn = blockIdx.y * 128;
  const int k0 = blockIdx.z * kslice;

  const int wr = (wave >> 1) * 64;  // wave row base
  const int wc = (wave & 1) * 64;   // wave col base

  f32x4 acc[4][4] = {};

  // staging: per round, 256 threads move 32 rows x 64 cols (4KB); 4 rounds
  // each for A and B. wave w covers rows w*8..w*8+8 per round; lane l ->
  // row +(l>>3), chunk l&7 (source col pre-XOR-swizzled, rule 21).
  const int srow = wave * 8 + (lane >> 3);
  const int scol = ((lane & 7) ^ (lane >> 3)) * 8;    // swizzled source col
  const u16* ag = A + (size_t)(bm + srow) * lda + scol;
  const u16* bg = Bt + (size_t)(bn + srow) * ldb + scol;
  const int ldsbase = wave * 8 * 64;                  // shorts, wave-uniform

  auto STAGE = [&](int buf, int kt) {
    short* sA = &lds[buf][0];
    short* sB = &lds[buf][8192];
#pragma unroll
    for (int r = 0; r < 4; ++r)
      gload16(ag + (size_t)(r * 32) * lda + kt, sA + ldsbase + r * 32 * 64);
#pragma unroll
    for (int r = 0; r < 4; ++r)
      gload16(bg + (size_t)(r * 32) * ldb + kt, sB + ldsbase + r * 32 * 64);
  };

  auto COMPUTE = [&](int buf) {
    const short* sA = &lds[buf][0];
    const short* sB = &lds[buf][8192];
#pragma unroll
    for (int ks = 0; ks < 2; ++ks) {
      const int kos = (ks * 32 + (lane >> 4) * 8) ^ ((lane & 7) << 3);
      bf16x8 a[4], b[4];
#pragma unroll
      for (int m = 0; m < 4; ++m)
        a[m] = *(const bf16x8*)&sA[(wr + m * 16 + (lane & 15)) * 64 + kos];
#pragma unroll
      for (int n = 0; n < 4; ++n)
        b[n] = *(const bf16x8*)&sB[(wc + n * 16 + (lane & 15)) * 64 + kos];
#pragma unroll
      for (int m = 0; m < 4; ++m)
#pragma unroll
        for (int n = 0; n < 4; ++n)
          acc[m][n] = __builtin_amdgcn_mfma_f32_16x16x32_bf16(a[m], b[n], acc[m][n], 0, 0, 0);
    }
  };

  const int nt = kslice >> 6;
  STAGE(0, k0);
  __syncthreads();
  int cur = 0;
  for (int t = 0; t + 1 < nt; ++t) {
    STAGE(cur ^ 1, k0 + (t + 1) * 64);   // prefetch next tile (other buffer)
    COMPUTE(cur);                        // compute current under load latency
    __syncthreads();                     // vmcnt+lgkmcnt drain + barrier
    cur ^= 1;
  }
  COMPUTE(cur);

  float* Cfz = Cf + (size_t)blockIdx.z * zstride;
#pragma unroll
  for (int m = 0; m < 4; ++m) {
    const int row0 = bm + wr + m * 16 + (lane >> 4) * 4;
#pragma unroll
    for (int n = 0; n < 4; ++n) {
      const int col = bn + wc + n * 16 + (lane & 15);
      float badd = BIAS ? bias[col] : 0.f;
      f32x4 a4 = acc[m][n];
#pragma unroll
      for (int r = 0; r < 4; ++r) {
        float vv = a4[r] + badd;
        if (GELU) vv = 0.5f * vv * (1.f + erff(vv * 0.70710678118f));
        size_t idx = (size_t)(row0 + r) * ldc + col;
        if (OUTBF) Cb[idx] = f2bfbits(vv);
        else Cfz[idx] = vv;
      }
    }
  }
}

// ---------------------------------------------------------------------------
// Windowed (tridiagonal) attention for one head-group.
// One wave per (token, head-in-group). qkv: (NT, 3GN) bf16 [q|k|v blocks].
// ---------------------------------------------------------------------------
__global__ __launch_bounds__(256) void attn_window(const u16* __restrict__ qkv,
                                                   u16* __restrict__ ctx) {
  const int lane = threadIdx.x & 63;
  const int gw = blockIdx.x * 4 + (threadIdx.x >> 6);
  const int hh = gw % HG;
  const int t = gw / HG;
  const int s = t % S_;
  const size_t qb = (size_t)t * G3 + hh * K_ + lane * 8;

  float qf[8];
  {
    bf16x8 q8 = *(const bf16x8*)(qkv + qb);
#pragma unroll
    for (int e = 0; e < 8; ++e) qf[e] = bits2f((u16)q8[e]);
  }

  const bool val0 = (s > 0), val2 = (s < S_ - 1);
  float dot[3] = {0.f, 0.f, 0.f};
  float vf[3][8];
#pragma unroll
  for (int j = 0; j < 3; ++j) {
    if ((j == 0 && !val0) || (j == 2 && !val2)) continue;
    const size_t nb = qb + (size_t)(j - 1) * G3;
    bf16x8 k8 = *(const bf16x8*)(qkv + nb + GN);
    bf16x8 v8 = *(const bf16x8*)(qkv + nb + 2 * GN);
    float d = 0.f;
#pragma unroll
    for (int e = 0; e < 8; ++e) {
      d += qf[e] * bits2f((u16)k8[e]);
      vf[j][e] = bits2f((u16)v8[e]);
    }
    dot[j] = d;
  }
#pragma unroll
  for (int j = 0; j < 3; ++j) {
    float d = dot[j];
    for (int m = 32; m >= 1; m >>= 1) d += __shfl_xor(d, m);
    dot[j] = d;
  }
  const float scale = 0.044194173824159f;  // 1/sqrt(512)
  float sc[3];
  sc[0] = val0 ? dot[0] * scale : -1e30f;
  sc[1] = dot[1] * scale;
  sc[2] = val2 ? dot[2] * scale : -1e30f;
  float mx = fmaxf(sc[0], fmaxf(sc[1], sc[2]));
  float p[3], sum = 0.f;
#pragma unroll
  for (int j = 0; j < 3; ++j) {
    p[j] = (sc[j] > -1e29f) ? expf(sc[j] - mx) : 0.f;
    sum += p[j];
  }
  const float inv = 1.f / sum;
  float o[8] = {0.f, 0.f, 0.f, 0.f, 0.f, 0.f, 0.f, 0.f};
#pragma unroll
  for (int j = 0; j < 3; ++j) {
    if ((j == 0 && !val0) || (j == 2 && !val2)) continue;
    const float pj = p[j] * inv;
#pragma unroll
    for (int e = 0; e < 8; ++e) o[e] += pj * vf[j][e];
  }
  bf16x8 o8;
#pragma unroll
  for (int e = 0; e < 8; ++e) o8[e] = (short)f2bfbits(o[e]);
  *(bf16x8*)(ctx + (size_t)t * HK + hh * K_ + lane * 8) = o8;
}

// ---------------------------------------------------------------------------
// y = xres + sum(parts) (+bias); out = LN(y)*gamma+beta -> fp32 / bf16
// ---------------------------------------------------------------------------
__global__ __launch_bounds__(256) void resid_ln(const float* __restrict__ xres,
                                                const float* __restrict__ parts,
                                                int nparts, size_t pstride,
                                                const float* __restrict__ bias,
                                                const float* __restrict__ gamma,
                                                const float* __restrict__ beta,
                                                float* __restrict__ outf,
                                                u16* __restrict__ outb) {
  const int row = blockIdx.x;
  const int tid = threadIdx.x;
  const size_t base = (size_t)row * D_;
  float2 xv = ((const float2*)(xres + base))[tid];
  float y0 = xv.x, y1 = xv.y;
  for (int p = 0; p < nparts; ++p) {
    float2 pv = ((const float2*)(parts + p * pstride + base))[tid];
    y0 += pv.x; y1 += pv.y;
  }
  if (bias) {
    float2 bv = ((const float2*)bias)[tid];
    y0 += bv.x; y1 += bv.y;
  }
  float s = y0 + y1, ss = y0 * y0 + y1 * y1;
  for (int m = 32; m >= 1; m >>= 1) { s += __shfl_xor(s, m); ss += __shfl_xor(ss, m); }
  __shared__ float red[8];
  const int wave = tid >> 6, lane = tid & 63;
  if (lane == 0) { red[wave] = s; red[4 + wave] = ss; }
  __syncthreads();
  s = red[0] + red[1] + red[2] + red[3];
  ss = red[4] + red[5] + red[6] + red[7];
  const float mean = s * (1.f / D_);
  const float var = ss * (1.f / D_) - mean * mean;
  const float rstd = rsqrtf(var + 1e-3f);
  float2 gv = ((const float2*)gamma)[tid];
  float2 bev = ((const float2*)beta)[tid];
  float o0 = (y0 - mean) * rstd * gv.x + bev.x;
  float o1 = (y1 - mean) * rstd * gv.y + bev.y;
  if (outf) { float2 of; of.x = o0; of.y = o1; ((float2*)(outf + base))[tid] = of; }
  if (outb) { ushort2 ob; ob.x = f2bfbits(o0); ob.y = f2bfbits(o1); ((ushort2*)(outb + base))[tid] = ob; }
}

// ---------------------------------------------------------------------------
extern "C" void kernel_launch(void* const* d_in, const int* in_sizes, int n_in,
                              void* d_out, int out_size, void* d_ws, size_t ws_size,
                              hipStream_t stream) {
  const float* x  = (const float*)d_in[0];
  const float* Wq = (const float*)d_in[1];
  const float* bq = (const float*)d_in[2];
  const float* Wk = (const float*)d_in[3];
  const float* bk = (const float*)d_in[4];
  const float* Wv = (const float*)d_in[5];
  const float* bv = (const float*)d_in[6];
  const float* Wo = (const float*)d_in[7];
  const float* bo = (const float*)d_in[8];
  const float* W1 = (const float*)d_in[9];
  const float* b1 = (const float*)d_in[10];
  const float* W2 = (const float*)d_in[11];
  const float* b2 = (const float*)d_in[12];
  const float* g1 = (const float*)d_in[13];
  const float* be1 = (const float*)d_in[14];
  const float* g2 = (const float*)d_in[15];
  const float* be2 = (const float*)d_in[16];
  float* out = (float*)d_out;

  char* w = (char*)d_ws;
  size_t o = 0;
  auto nxt = [&](size_t bytes) -> char* {
    char* p = w + o;
    o += (bytes + 255) & ~(size_t)255;
    return p;
  };
  u16* xb     = (u16*)nxt((size_t)NT * D_ * 2);
  u16* wqkvt  = (u16*)nxt((size_t)3 * HK * D_ * 2);   // [g][3][GN][D]
  u16* wot    = (u16*)nxt((size_t)D_ * HK * 2);
  u16* w1t    = (u16*)nxt((size_t)F_ * D_ * 2);
  u16* w2t    = (u16*)nxt((size_t)D_ * F_ * 2);
  float* qkvbias = (float*)nxt((size_t)NGROUP * G3 * 4);
  u16* qkvg   = (u16*)nxt((size_t)NT * G3 * 2);       // 50.3MB
  char* extraA = nxt((size_t)NT * D_ * 4);            // 16.8MB pad after qkvg
  u16* ctxb   = (u16*)nxt((size_t)NT * HK * 2);       // 67.1MB
  float* out1f = (float*)nxt((size_t)NT * D_ * 4);
  u16* out1b   = (u16*)nxt((size_t)NT * D_ * 2);
  (void)extraA;
  float* woP  = (float*)qkvg;   // 2x f32 WO partials (qkvg region, 33.6MB)
  u16*   hb   = (u16*)qkvg;     // FFN1 output, live after LN1
  float* ffnP = (float*)ctxb;   // 2x f32 FFN2 partials (ctxb region)

  // --- input/weight conversions ---
  conv_f32_bf16<<<dim3(NT * D_ / 4 / 256), 256, 0, stream>>>(x, xb, NT * D_ / 4);
  for (int g = 0; g < NGROUP; ++g) {
    transpose_f32_bf16<<<dim3(GN / 32, D_ / 32), 256, 0, stream>>>(
        Wq + g * GN, HK, wqkvt + ((size_t)(g * 3 + 0) * GN) * D_, D_, GN);
    transpose_f32_bf16<<<dim3(GN / 32, D_ / 32), 256, 0, stream>>>(
        Wk + g * GN, HK, wqkvt + ((size_t)(g * 3 + 1) * GN) * D_, D_, GN);
    transpose_f32_bf16<<<dim3(GN / 32, D_ / 32), 256, 0, stream>>>(
        Wv + g * GN, HK, wqkvt + ((size_t)(g * 3 + 2) * GN) * D_, D_, GN);
  }
  transpose_f32_bf16<<<dim3(D_ / 32, HK / 32), 256, 0, stream>>>(Wo, D_, wot, HK, D_);
  transpose_f32_bf16<<<dim3(F_ / 32, D_ / 32), 256, 0, stream>>>(W1, F_, w1t, D_, F_);
  transpose_f32_bf16<<<dim3(D_ / 32, F_ / 32), 256, 0, stream>>>(W2, D_, w2t, F_, D_);
  qkv_bias_cat<<<dim3(NGROUP * G3 / 256), 256, 0, stream>>>(bq, bk, bv, qkvbias);

  // --- attention by head-groups: fused QKV gemm -> windowed attn ---
  for (int g = 0; g < NGROUP; ++g) {
    gemm128d<1, 0, 1><<<dim3(64, G3 / 128, 1), 256, 0, stream>>>(
        xb, D_, wqkvt + (size_t)g * G3 * D_, D_, qkvbias + g * G3,
        nullptr, 0, qkvg, G3, D_);
    attn_window<<<dim3(NT * HG / 4), 256, 0, stream>>>(qkvg, ctxb + (size_t)g * HG * K_);
  }

  // --- WO: woP[z] = ctx @ Wo (split-K=2 partials, no atomics) ---
  gemm128d<0, 0, 0><<<dim3(64, 4, 2), 256, 0, stream>>>(
      ctxb, HK, wot, HK, nullptr, woP, (size_t)NT * D_, nullptr, D_, 2048);

  // --- LN1: out1 = LN(x + sum(woP) + bo) ---
  resid_ln<<<dim3(NT), 256, 0, stream>>>(x, woP, 2, (size_t)NT * D_, bo,
                                         g1, be1, out1f, out1b);

  // --- FFN1: hb = gelu(out1 @ W1 + b1) ---
  gemm128d<1, 1, 1><<<dim3(64, F_ / 128, 1), 256, 0, stream>>>(
      out1b, D_, w1t, D_, b1, nullptr, 0, hb, F_, D_);

  // --- FFN2: ffnP[z] = hb @ W2 (split-K=2 partials; b2 folded into LN2) ---
  gemm128d<0, 0, 0><<<dim3(64, 4, 2), 256, 0, stream>>>(
      hb, F_, w2t, F_, nullptr, ffnP, (size_t)NT * D_, nullptr, D_, 1024);

  // --- LN2: out = LN(out1 + sum(ffnP) + b2) ---
  resid_ln<<<dim3(NT), 256, 0, stream>>>(out1f, ffnP, 2, (size_t)NT * D_, b2,
                                         g2, be2, out, nullptr);

  (void)in_sizes; (void)n_in; (void)out_size; (void)ws_size;
}

// Round 6
// 362.727 us; speedup vs baseline: 1.2313x; 1.1009x over previous
//
#include <hip/hip_runtime.h>
#include <hip/hip_bf16.h>
#include <math.h>

#define B_ 4
#define S_ 2048
#define D_ 512
#define H_ 8
#define K_ 512
#define F_ 2048
#define NT 8192     // B*S tokens
#define HK 4096     // H*K
#define HG 2        // heads per group
#define NGROUP 4    // H/HG
#define GN 1024     // HG*K columns per group
#define G3 3072     // 3*GN

typedef __attribute__((ext_vector_type(8))) short bf16x8;
typedef __attribute__((ext_vector_type(4))) float f32x4;
typedef unsigned short u16;

__device__ __forceinline__ float bits2f(u16 b) {
  union { unsigned u; float f; } c; c.u = ((unsigned)b) << 16; return c.f;
}
__device__ __forceinline__ u16 f2bfbits(float f) {
  union { float f; unsigned u; } c; c.f = f;
  unsigned r = c.u + 0x7fffu + ((c.u >> 16) & 1u);
  return (u16)(r >> 16);
}

__device__ __forceinline__ void gload16(const void* g, void* lds) {
  __builtin_amdgcn_global_load_lds(
      (const __attribute__((address_space(1))) unsigned int*)g,
      (__attribute__((address_space(3))) unsigned int*)lds, 16, 0, 0);
}

// ---------------------------------------------------------------------------
// ALL preprocessing in ONE launch (replaces 15 transposes + bias cat + conv):
//   id      0..6143 : Wq/Wk/Wv 32x32 transpose tiles -> wqkvt [g][p][GN][D]
//   6144..8191      : Wo tiles -> wot [D][HK]
//   8192..9215      : W1 tiles -> w1t [F][D]
//   9216..10239     : W2 tiles -> w2t [D][F]
//   10240..10287    : qkv bias concat (48 * 256 = 12288 elems)
//   10288..14383    : x fp32 -> bf16 (4096 * 256 float4 = NT*D)
// ---------------------------------------------------------------------------
__global__ __launch_bounds__(256) void prep_all(
    const float* __restrict__ Wq, const float* __restrict__ Wk,
    const float* __restrict__ Wv, const float* __restrict__ Wo,
    const float* __restrict__ W1, const float* __restrict__ W2,
    const float* __restrict__ bq, const float* __restrict__ bk,
    const float* __restrict__ bv, const float* __restrict__ x,
    u16* __restrict__ wqkvt, u16* __restrict__ wot,
    u16* __restrict__ w1t, u16* __restrict__ w2t,
    float* __restrict__ qkvbias, u16* __restrict__ xb) {
  const int id = blockIdx.x;
  const int tid = threadIdx.x;
  if (id >= 10240) {
    if (id < 10288) {                    // qkv bias concat
      int i = (id - 10240) * 256 + tid;  // < NGROUP*G3
      int g = i / G3, r = i % G3;
      int part = r / GN, off = r % GN;
      const float* src = (part == 0) ? bq : (part == 1) ? bk : bv;
      qkvbias[i] = src[g * GN + off];
    } else {                             // x conversion (exact: 4096 blocks)
      int i = (id - 10288) * 256 + tid;
      float4 f = ((const float4*)x)[i];
      ushort4 o;
      o.x = f2bfbits(f.x); o.y = f2bfbits(f.y);
      o.z = f2bfbits(f.z); o.w = f2bfbits(f.w);
      ((ushort4*)xb)[i] = o;
    }
    return;
  }
  __shared__ float tile[32][33];
  const int tx = tid & 31;
  const int ty = tid >> 5;               // 0..7
  const float* src;
  u16* dst;
  int rb, cb, ldin, ldout, QKV = 0, part = 0;
  if (id < 6144) {                       // Wq/Wk/Wv: src [D][HK]
    part = id / 2048;
    int rem = id % 2048;
    rb = (rem & 15) * 32;                // d
    cb = (rem >> 4) * 32;                // n in [0,HK)
    src = (part == 0) ? Wq : (part == 1) ? Wk : Wv;
    ldin = HK; dst = wqkvt; ldout = D_; QKV = 1;
  } else if (id < 8192) {                // Wo: src [HK][D] -> wot [D][HK]
    int rem = id - 6144;
    rb = (rem >> 4) * 32;                // k in [0,HK)
    cb = (rem & 15) * 32;                // n in [0,D)
    src = Wo; ldin = D_; dst = wot; ldout = HK;
  } else if (id < 9216) {                // W1: src [D][F] -> w1t [F][D]
    int rem = id - 8192;
    rb = (rem & 15) * 32;                // d
    cb = (rem >> 4) * 32;                // n in [0,F)
    src = W1; ldin = F_; dst = w1t; ldout = D_;
  } else {                               // W2: src [F][D] -> w2t [D][F]
    int rem = id - 9216;
    rb = (rem >> 4) * 32;                // f in [0,F)
    cb = (rem & 15) * 32;                // n in [0,D)
    src = W2; ldin = D_; dst = w2t; ldout = F_;
  }
  for (int i = ty; i < 32; i += 8)
    tile[i][tx] = src[(size_t)(rb + i) * ldin + cb + tx];
  __syncthreads();
  for (int i = ty; i < 32; i += 8) {
    int n = cb + i;
    int drow = QKV ? ((((n >> 10) * 3 + part) << 10) | (n & 1023)) : n;
    dst[(size_t)drow * ldout + rb + tx] = f2bfbits(tile[tx][i]);
  }
}

// ---------------------------------------------------------------------------
// bf16 GEMM, 128x128 tile, BK=64, 4 waves (2x2 of 64x64), double-buffered
// LDS (64KB -> 2 blocks/CU for cross-block overlap), 2-phase pipeline:
// issue next tile's global_load_lds BEFORE computing the current tile;
// single __syncthreads() per K-tile. T2 XOR swizzle via pre-swizzled global
// source + swizzled LDS read (proven 0-conflict in r2-r5).
// OUTBF: 1 = bf16 store (+bias)(+gelu), 0 = f32 partial store at
//        Cf + blockIdx.z * zstride (split-K).
// ---------------------------------------------------------------------------
template <int BIAS, int GELU, int OUTBF>
__global__ __launch_bounds__(256) void gemm128d(const u16* __restrict__ A, int lda,
                                                const u16* __restrict__ Bt, int ldb,
                                                const float* __restrict__ bias,
                                                float* __restrict__ Cf, size_t zstride,
                                                u16* __restrict__ Cb, int ldc,
                                                int kslice) {
  __shared__ short lds[2][16384];   // per buf: A[128][64] @0, B[128][64] @8192
  const int tid = threadIdx.x;
  const int lane = tid & 63;
  const int wave = tid >> 6;        // 0..3
  const int bm = blockIdx.x * 128;
  const int bn = blockIdx.y * 128;
  const int k0 = blockIdx.z * kslice;

  const int wr = (wave >> 1) * 64;  // wave row base
  const int wc = (wave & 1) * 64;   // wave col base

  f32x4 acc[4][4] = {};

  // staging: per round, 256 threads move 32 rows x 64 cols (4KB); 4 rounds
  // each for A and B. wave w covers rows w*8..w*8+8 per round; lane l ->
  // row +(l>>3), chunk l&7 (source col pre-XOR-swizzled, rule 21).
  const int srow = wave * 8 + (lane >> 3);
  const int scol = ((lane & 7) ^ (lane >> 3)) * 8;    // swizzled source col
  const u16* ag = A + (size_t)(bm + srow) * lda + scol;
  const u16* bg = Bt + (size_t)(bn + srow) * ldb + scol;
  const int ldsbase = wave * 8 * 64;                  // shorts, wave-uniform

  auto STAGE = [&](int buf, int kt) {
    short* sA = &lds[buf][0];
    short* sB = &lds[buf][8192];
#pragma unroll
    for (int r = 0; r < 4; ++r)
      gload16(ag + (size_t)(r * 32) * lda + kt, sA + ldsbase + r * 32 * 64);
#pragma unroll
    for (int r = 0; r < 4; ++r)
      gload16(bg + (size_t)(r * 32) * ldb + kt, sB + ldsbase + r * 32 * 64);
  };

  auto COMPUTE = [&](int buf) {
    const short* sA = &lds[buf][0];
    const short* sB = &lds[buf][8192];
#pragma unroll
    for (int ks = 0; ks < 2; ++ks) {
      const int kos = (ks * 32 + (lane >> 4) * 8) ^ ((lane & 7) << 3);
      bf16x8 a[4], b[4];
#pragma unroll
      for (int m = 0; m < 4; ++m)
        a[m] = *(const bf16x8*)&sA[(wr + m * 16 + (lane & 15)) * 64 + kos];
#pragma unroll
      for (int n = 0; n < 4; ++n)
        b[n] = *(const bf16x8*)&sB[(wc + n * 16 + (lane & 15)) * 64 + kos];
#pragma unroll
      for (int m = 0; m < 4; ++m)
#pragma unroll
        for (int n = 0; n < 4; ++n)
          acc[m][n] = __builtin_amdgcn_mfma_f32_16x16x32_bf16(a[m], b[n], acc[m][n], 0, 0, 0);
    }
  };

  const int nt = kslice >> 6;
  STAGE(0, k0);
  __syncthreads();
  int cur = 0;
  for (int t = 0; t + 1 < nt; ++t) {
    STAGE(cur ^ 1, k0 + (t + 1) * 64);   // prefetch next tile (other buffer)
    COMPUTE(cur);                        // compute current under load latency
    __syncthreads();                     // vmcnt+lgkmcnt drain + barrier
    cur ^= 1;
  }
  COMPUTE(cur);

  float* Cfz = Cf + (size_t)blockIdx.z * zstride;
#pragma unroll
  for (int m = 0; m < 4; ++m) {
    const int row0 = bm + wr + m * 16 + (lane >> 4) * 4;
#pragma unroll
    for (int n = 0; n < 4; ++n) {
      const int col = bn + wc + n * 16 + (lane & 15);
      float badd = BIAS ? bias[col] : 0.f;
      f32x4 a4 = acc[m][n];
#pragma unroll
      for (int r = 0; r < 4; ++r) {
        float vv = a4[r] + badd;
        if (GELU) vv = 0.5f * vv * (1.f + erff(vv * 0.70710678118f));
        size_t idx = (size_t)(row0 + r) * ldc + col;
        if (OUTBF) Cb[idx] = f2bfbits(vv);
        else Cfz[idx] = vv;
      }
    }
  }
}

// ---------------------------------------------------------------------------
// Windowed (tridiagonal) attention for one head-group.
// One wave per (token, head-in-group). qkv: (NT, 3GN) bf16 [q|k|v blocks].
// ---------------------------------------------------------------------------
__global__ __launch_bounds__(256) void attn_window(const u16* __restrict__ qkv,
                                                   u16* __restrict__ ctx) {
  const int lane = threadIdx.x & 63;
  const int gw = blockIdx.x * 4 + (threadIdx.x >> 6);
  const int hh = gw % HG;
  const int t = gw / HG;
  const int s = t % S_;
  const size_t qb = (size_t)t * G3 + hh * K_ + lane * 8;

  float qf[8];
  {
    bf16x8 q8 = *(const bf16x8*)(qkv + qb);
#pragma unroll
    for (int e = 0; e < 8; ++e) qf[e] = bits2f((u16)q8[e]);
  }

  const bool val0 = (s > 0), val2 = (s < S_ - 1);
  float dot[3] = {0.f, 0.f, 0.f};
  float vf[3][8];
#pragma unroll
  for (int j = 0; j < 3; ++j) {
    if ((j == 0 && !val0) || (j == 2 && !val2)) continue;
    const size_t nb = qb + (size_t)(j - 1) * G3;
    bf16x8 k8 = *(const bf16x8*)(qkv + nb + GN);
    bf16x8 v8 = *(const bf16x8*)(qkv + nb + 2 * GN);
    float d = 0.f;
#pragma unroll
    for (int e = 0; e < 8; ++e) {
      d += qf[e] * bits2f((u16)k8[e]);
      vf[j][e] = bits2f((u16)v8[e]);
    }
    dot[j] = d;
  }
#pragma unroll
  for (int j = 0; j < 3; ++j) {
    float d = dot[j];
    for (int m = 32; m >= 1; m >>= 1) d += __shfl_xor(d, m);
    dot[j] = d;
  }
  const float scale = 0.044194173824159f;  // 1/sqrt(512)
  float sc[3];
  sc[0] = val0 ? dot[0] * scale : -1e30f;
  sc[1] = dot[1] * scale;
  sc[2] = val2 ? dot[2] * scale : -1e30f;
  float mx = fmaxf(sc[0], fmaxf(sc[1], sc[2]));
  float p[3], sum = 0.f;
#pragma unroll
  for (int j = 0; j < 3; ++j) {
    p[j] = (sc[j] > -1e29f) ? expf(sc[j] - mx) : 0.f;
    sum += p[j];
  }
  const float inv = 1.f / sum;
  float o[8] = {0.f, 0.f, 0.f, 0.f, 0.f, 0.f, 0.f, 0.f};
#pragma unroll
  for (int j = 0; j < 3; ++j) {
    if ((j == 0 && !val0) || (j == 2 && !val2)) continue;
    const float pj = p[j] * inv;
#pragma unroll
    for (int e = 0; e < 8; ++e) o[e] += pj * vf[j][e];
  }
  bf16x8 o8;
#pragma unroll
  for (int e = 0; e < 8; ++e) o8[e] = (short)f2bfbits(o[e]);
  *(bf16x8*)(ctx + (size_t)t * HK + hh * K_ + lane * 8) = o8;
}

// ---------------------------------------------------------------------------
// y = xres + sum(parts) (+bias); out = LN(y)*gamma+beta -> fp32 / bf16
// ---------------------------------------------------------------------------
__global__ __launch_bounds__(256) void resid_ln(const float* __restrict__ xres,
                                                const float* __restrict__ parts,
                                                int nparts, size_t pstride,
                                                const float* __restrict__ bias,
                                                const float* __restrict__ gamma,
                                                const float* __restrict__ beta,
                                                float* __restrict__ outf,
                                                u16* __restrict__ outb) {
  const int row = blockIdx.x;
  const int tid = threadIdx.x;
  const size_t base = (size_t)row * D_;
  float2 xv = ((const float2*)(xres + base))[tid];
  float y0 = xv.x, y1 = xv.y;
  for (int p = 0; p < nparts; ++p) {
    float2 pv = ((const float2*)(parts + p * pstride + base))[tid];
    y0 += pv.x; y1 += pv.y;
  }
  if (bias) {
    float2 bv = ((const float2*)bias)[tid];
    y0 += bv.x; y1 += bv.y;
  }
  float s = y0 + y1, ss = y0 * y0 + y1 * y1;
  for (int m = 32; m >= 1; m >>= 1) { s += __shfl_xor(s, m); ss += __shfl_xor(ss, m); }
  __shared__ float red[8];
  const int wave = tid >> 6, lane = tid & 63;
  if (lane == 0) { red[wave] = s; red[4 + wave] = ss; }
  __syncthreads();
  s = red[0] + red[1] + red[2] + red[3];
  ss = red[4] + red[5] + red[6] + red[7];
  const float mean = s * (1.f / D_);
  const float var = ss * (1.f / D_) - mean * mean;
  const float rstd = rsqrtf(var + 1e-3f);
  float2 gv = ((const float2*)gamma)[tid];
  float2 bev = ((const float2*)beta)[tid];
  float o0 = (y0 - mean) * rstd * gv.x + bev.x;
  float o1 = (y1 - mean) * rstd * gv.y + bev.y;
  if (outf) { float2 of; of.x = o0; of.y = o1; ((float2*)(outf + base))[tid] = of; }
  if (outb) { ushort2 ob; ob.x = f2bfbits(o0); ob.y = f2bfbits(o1); ((ushort2*)(outb + base))[tid] = ob; }
}

// ---------------------------------------------------------------------------
extern "C" void kernel_launch(void* const* d_in, const int* in_sizes, int n_in,
                              void* d_out, int out_size, void* d_ws, size_t ws_size,
                              hipStream_t stream) {
  const float* x  = (const float*)d_in[0];
  const float* Wq = (const float*)d_in[1];
  const float* bq = (const float*)d_in[2];
  const float* Wk = (const float*)d_in[3];
  const float* bk = (const float*)d_in[4];
  const float* Wv = (const float*)d_in[5];
  const float* bv = (const float*)d_in[6];
  const float* Wo = (const float*)d_in[7];
  const float* bo = (const float*)d_in[8];
  const float* W1 = (const float*)d_in[9];
  const float* b1 = (const float*)d_in[10];
  const float* W2 = (const float*)d_in[11];
  const float* b2 = (const float*)d_in[12];
  const float* g1 = (const float*)d_in[13];
  const float* be1 = (const float*)d_in[14];
  const float* g2 = (const float*)d_in[15];
  const float* be2 = (const float*)d_in[16];
  float* out = (float*)d_out;

  char* w = (char*)d_ws;
  size_t o = 0;
  auto nxt = [&](size_t bytes) -> char* {
    char* p = w + o;
    o += (bytes + 255) & ~(size_t)255;
    return p;
  };
  u16* xb     = (u16*)nxt((size_t)NT * D_ * 2);
  u16* wqkvt  = (u16*)nxt((size_t)3 * HK * D_ * 2);   // [g][3][GN][D]
  u16* wot    = (u16*)nxt((size_t)D_ * HK * 2);
  u16* w1t    = (u16*)nxt((size_t)F_ * D_ * 2);
  u16* w2t    = (u16*)nxt((size_t)D_ * F_ * 2);
  float* qkvbias = (float*)nxt((size_t)NGROUP * G3 * 4);
  u16* qkvg   = (u16*)nxt((size_t)NT * G3 * 2);       // 50.3MB
  char* extraA = nxt((size_t)NT * D_ * 4);            // 16.8MB pad after qkvg
  u16* ctxb   = (u16*)nxt((size_t)NT * HK * 2);       // 67.1MB
  float* out1f = (float*)nxt((size_t)NT * D_ * 4);
  u16* out1b   = (u16*)nxt((size_t)NT * D_ * 2);
  (void)extraA;
  float* woP  = (float*)qkvg;   // 2x f32 WO partials (qkvg region, 33.6MB)
  u16*   hb   = (u16*)qkvg;     // FFN1 output, live after LN1
  float* ffnP = (float*)ctxb;   // 2x f32 FFN2 partials (ctxb region)

  // --- ALL prep in one launch ---
  prep_all<<<dim3(14384), 256, 0, stream>>>(Wq, Wk, Wv, Wo, W1, W2, bq, bk, bv,
                                            x, wqkvt, wot, w1t, w2t, qkvbias, xb);

  // --- attention by head-groups: fused QKV gemm -> windowed attn ---
  for (int g = 0; g < NGROUP; ++g) {
    gemm128d<1, 0, 1><<<dim3(64, G3 / 128, 1), 256, 0, stream>>>(
        xb, D_, wqkvt + (size_t)g * G3 * D_, D_, qkvbias + g * G3,
        nullptr, 0, qkvg, G3, D_);
    attn_window<<<dim3(NT * HG / 4), 256, 0, stream>>>(qkvg, ctxb + (size_t)g * HG * K_);
  }

  // --- WO: woP[z] = ctx @ Wo (split-K=2 partials, no atomics) ---
  gemm128d<0, 0, 0><<<dim3(64, 4, 2), 256, 0, stream>>>(
      ctxb, HK, wot, HK, nullptr, woP, (size_t)NT * D_, nullptr, D_, 2048);

  // --- LN1: out1 = LN(x + sum(woP) + bo) ---
  resid_ln<<<dim3(NT), 256, 0, stream>>>(x, woP, 2, (size_t)NT * D_, bo,
                                         g1, be1, out1f, out1b);

  // --- FFN1: hb = gelu(out1 @ W1 + b1) ---
  gemm128d<1, 1, 1><<<dim3(64, F_ / 128, 1), 256, 0, stream>>>(
      out1b, D_, w1t, D_, b1, nullptr, 0, hb, F_, D_);

  // --- FFN2: ffnP[z] = hb @ W2 (split-K=2 partials; b2 folded into LN2) ---
  gemm128d<0, 0, 0><<<dim3(64, 4, 2), 256, 0, stream>>>(
      hb, F_, w2t, F_, nullptr, ffnP, (size_t)NT * D_, nullptr, D_, 1024);

  // --- LN2: out = LN(out1 + sum(ffnP) + b2) ---
  resid_ln<<<dim3(NT), 256, 0, stream>>>(out1f, ffnP, 2, (size_t)NT * D_, b2,
                                         g2, be2, out, nullptr);

  (void)in_sizes; (void)n_in; (void)out_size; (void)ws_size;
}